// Round 8
// baseline (132.971 us; speedup 1.0000x reference)
//
#include <hip/hip_runtime.h>
#include <stdint.h>

#define D    300
#define K    10

#define CHUNK_ROWS   64
#define CHUNK_FLOATS (CHUNK_ROWS * D)     // 19200 floats
#define CHUNK_BYTES  (CHUNK_FLOATS * 4)   // 76800 B = 75 x 1024
#define NLOADS       75                   // 1024 B per wave-load instruction
#define NBLK         256                  // 1 block per CU (LDS-bound)

#define P2_BLOCKS  256
#define P2_THREADS 1024
#define P2_CPT     2       // ceil(400000/256/1024)
#define NCAND      (P2_BLOCKS * K)   // 2560
#define F_CPT      3       // ceil(2560/1024)

typedef float f32x4 __attribute__((ext_vector_type(4)));

__device__ __forceinline__ float d4(f32x4 a, f32x4 b) {
    return a[0]*b[0] + a[1]*b[1] + a[2]*b[2] + a[3]*b[3];
}

#define RED16(x) { x += __shfl_xor(x, 8, 64); x += __shfl_xor(x, 4, 64); \
                   x += __shfl_xor(x, 2, 64); x += __shfl_xor(x, 1, 64); }

// ---------------- Phase 1: cosine via linear global->LDS DMA staging ----------------
// Block stages 64-row chunks (75 x 1024B aligned contiguous wave-loads) into a
// double-buffered LDS tile; 16-lane groups compute dot/norm from LDS.
__global__ __launch_bounds__(256) void cos_all_lds(
    const float* __restrict__ emb, const float* __restrict__ wvec,
    float* __restrict__ score, int V)
{
    extern __shared__ float lds[];        // 2 * 19200 floats = 153600 B
    const int tid  = threadIdx.x;
    const int lane = tid & 63;
    const int wid  = tid >> 6;
    const int l16  = lane & 15;
    const int grp  = tid >> 4;            // block-wide group id 0..15
    const bool tl  = (l16 < 11);          // 75 - 64 = 11 tail lanes

    // w fragments (per l16 slot)
    const f32x4* w4p = (const f32x4*)wvec;
    f32x4 w0 = w4p[l16];
    f32x4 w1 = w4p[l16 + 16];
    f32x4 w2 = w4p[l16 + 32];
    f32x4 w3 = w4p[l16 + 48];
    f32x4 w4t = 0.f;
    if (tl) w4t = w4p[l16 + 64];

    float qsq = d4(w0,w0)+d4(w1,w1)+d4(w2,w2)+d4(w3,w3)+d4(w4t,w4t);
    RED16(qsq);
    const float qn = sqrtf(qsq);

    const int nchunks = V / CHUNK_ROWS;   // 6250 for V=400000 (exact)

    // stage chunk c into LDS buffer b: 75 aligned contiguous 1024B wave-loads,
    // round-robined across the 4 waves. Global src per-lane, LDS dst uniform.
#define STAGE(c, b)                                                            \
    {                                                                          \
        const uint8_t* gbase = (const uint8_t*)emb + (size_t)(c) * CHUNK_BYTES;\
        uint8_t* lbase = (uint8_t*)lds + (size_t)(b) * CHUNK_BYTES;            \
        for (int j = wid; j < NLOADS; j += 4) {                                \
            __builtin_amdgcn_global_load_lds(                                  \
                (const __attribute__((address_space(1))) void*)                \
                    (gbase + j * 1024 + lane * 16),                            \
                (__attribute__((address_space(3))) void*)(lbase + j * 1024),   \
                16, 0, 0);                                                     \
        }                                                                      \
    }

    int c   = blockIdx.x;
    int cur = 0;
    if (c < nchunks) STAGE(c, 0);

    for (; c < nchunks; c += NBLK, cur ^= 1) {
        asm volatile("s_waitcnt vmcnt(0)" ::: "memory");  // this wave's loads done
        __syncthreads();                                   // => all waves' loads done
        const int cn = c + NBLK;
        if (cn < nchunks) STAGE(cn, cur ^ 1);              // prefetch next chunk

        const float* lb = lds + cur * CHUNK_FLOATS;
        #pragma unroll
        for (int rr = 0; rr < 4; ++rr) {
            const int row = grp * 4 + rr;
            const f32x4* rp = (const f32x4*)(lb + row * D);
            f32x4 a0 = rp[l16];
            f32x4 a1 = rp[l16 + 16];
            f32x4 a2 = rp[l16 + 32];
            f32x4 a3 = rp[l16 + 48];
            f32x4 a4 = 0.f;
            if (tl) a4 = rp[l16 + 64];

            float da = d4(a0,w0) + d4(a1,w1);
            float db = d4(a2,w2) + d4(a3,w3) + d4(a4,w4t);
            float sa = d4(a0,a0) + d4(a1,a1);
            float sb = d4(a2,a2) + d4(a3,a3) + d4(a4,a4);
            float dot = da + db;
            float sq  = sa + sb;
            RED16(dot); RED16(sq);
            float cv = dot / (sqrtf(sq + 1e-9f) * qn);
            if (l16 == 0) score[c * CHUNK_ROWS + row] = cv;
        }
        // buffer reuse is ordered by next iteration's vmcnt+barrier
    }
#undef STAGE

    // leftover rows if V % CHUNK_ROWS != 0 (dead for V=400000, kept for safety)
    const int rem0 = nchunks * CHUNK_ROWS;
    for (int r = rem0 + blockIdx.x * 16 + grp; r < V; r += NBLK * 16) {
        const f32x4* rp = (const f32x4*)(emb + (size_t)r * D);
        f32x4 a0 = rp[l16];
        f32x4 a1 = rp[l16 + 16];
        f32x4 a2 = rp[l16 + 32];
        f32x4 a3 = rp[l16 + 48];
        f32x4 a4 = 0.f;
        if (tl) a4 = rp[l16 + 64];
        float da = d4(a0,w0) + d4(a1,w1);
        float db = d4(a2,w2) + d4(a3,w3) + d4(a4,w4t);
        float sa = d4(a0,a0) + d4(a1,a1);
        float sb = d4(a2,a2) + d4(a3,a3) + d4(a4,a4);
        float dot = da + db;
        float sq  = sa + sb;
        RED16(dot); RED16(sq);
        float cv = dot / (sqrtf(sq + 1e-9f) * qn);
        if (l16 == 0) score[r] = cv;
    }
}

// ---------------- Phase 2a: exact per-block top-10 over score chunks ----------------
__global__ __launch_bounds__(P2_THREADS) void block_topk(
    const float* __restrict__ score, int V,
    float* __restrict__ cand_v, int* __restrict__ cand_i)
{
    __shared__ float rv[16];
    __shared__ int   rp[16];
    __shared__ int   s_bp;

    const int tid  = threadIdx.x;
    const int lane = tid & 63;
    const int wid  = tid >> 6;
    const int per  = (V + P2_BLOCKS - 1) / P2_BLOCKS;
    const int base = blockIdx.x * per;

    float v[P2_CPT];
    #pragma unroll
    for (int t = 0; t < P2_CPT; ++t) {
        int i = tid + t * P2_THREADS;
        v[t] = (i < per && base + i < V) ? score[base + i] : -3e38f;
    }

    for (int p = 0; p < K; ++p) {
        float bestv = -3e38f; int bestpos = 0x7fffffff;
        #pragma unroll
        for (int t = 0; t < P2_CPT; ++t) {
            if (v[t] > bestv) { bestv = v[t]; bestpos = tid + t * P2_THREADS; }
        }
        #pragma unroll
        for (int m = 32; m >= 1; m >>= 1) {
            float ov = __shfl_xor(bestv, m, 64);
            int   op = __shfl_xor(bestpos, m, 64);
            if (ov > bestv || (ov == bestv && op < bestpos)) { bestv = ov; bestpos = op; }
        }
        if (lane == 0) { rv[wid] = bestv; rp[wid] = bestpos; }
        __syncthreads();
        if (tid == 0) {
            float bv = rv[0]; int bp = rp[0];
            for (int i = 1; i < 16; ++i)
                if (rv[i] > bv || (rv[i] == bv && rp[i] < bp)) { bv = rv[i]; bp = rp[i]; }
            cand_v[blockIdx.x*K + p] = bv;
            cand_i[blockIdx.x*K + p] = base + bp;
            s_bp = bp;
        }
        __syncthreads();
        const int wbp = s_bp;
        #pragma unroll
        for (int t = 0; t < P2_CPT; ++t) {
            if (tid + t * P2_THREADS == wbp) v[t] = -3e38f;
        }
        __syncthreads();
    }
}

// ---------------- Phase 2b: final top-10 over 2560 candidates ----------------
__global__ __launch_bounds__(P2_THREADS) void final_topk(
    const float* __restrict__ cand_v, const int* __restrict__ cand_i,
    float* __restrict__ out)
{
    __shared__ float rv[16];
    __shared__ int   rp[16];
    __shared__ int   s_bp;

    const int tid  = threadIdx.x;
    const int lane = tid & 63;
    const int wid  = tid >> 6;

    float v[F_CPT];
    #pragma unroll
    for (int t = 0; t < F_CPT; ++t) {
        int i = tid + t * P2_THREADS;
        v[t] = (i < NCAND) ? cand_v[i] : -3e38f;
    }

    for (int p = 0; p < K; ++p) {
        float bestv = -3e38f; int bestpos = 0x7fffffff;
        #pragma unroll
        for (int t = 0; t < F_CPT; ++t) {
            if (v[t] > bestv) { bestv = v[t]; bestpos = tid + t * P2_THREADS; }
        }
        #pragma unroll
        for (int m = 32; m >= 1; m >>= 1) {
            float ov = __shfl_xor(bestv, m, 64);
            int   op = __shfl_xor(bestpos, m, 64);
            if (ov > bestv || (ov == bestv && op < bestpos)) { bestv = ov; bestpos = op; }
        }
        if (lane == 0) { rv[wid] = bestv; rp[wid] = bestpos; }
        __syncthreads();
        if (tid == 0) {
            float bv = rv[0]; int bp = rp[0];
            for (int i = 1; i < 16; ++i)
                if (rv[i] > bv || (rv[i] == bv && rp[i] < bp)) { bv = rv[i]; bp = rp[i]; }
            out[p]     = bv;
            out[K + p] = (float)cand_i[bp];     // exact < 2^24
            s_bp = bp;
        }
        __syncthreads();
        const int wbp = s_bp;
        #pragma unroll
        for (int t = 0; t < F_CPT; ++t) {
            if (tid + t * P2_THREADS == wbp) v[t] = -3e38f;
        }
        __syncthreads();
    }
}

extern "C" void kernel_launch(void* const* d_in, const int* in_sizes, int n_in,
                              void* d_out, int out_size, void* d_ws, size_t ws_size,
                              hipStream_t stream) {
    const float* emb  = (const float*)d_in[0];
    const float* wvec = (const float*)d_in[1];
    const int V = in_sizes[0] / D;

    float* score  = (float*)d_ws;
    float* cand_v = score + V;
    int*   cand_i = (int*)(cand_v + NCAND);

    cos_all_lds<<<NBLK, 256, 2 * CHUNK_BYTES, stream>>>(emb, wvec, score, V);
    block_topk<<<P2_BLOCKS, P2_THREADS, 0, stream>>>(score, V, cand_v, cand_i);
    final_topk<<<1, P2_THREADS, 0, stream>>>(cand_v, cand_i, (float*)d_out);
}

// Round 9
// 119.361 us; speedup vs baseline: 1.1140x; 1.1140x over previous
//
#include <hip/hip_runtime.h>

#define D    300
#define NF4  75            // 300 floats = 75 float4 per row
#define K    10
#define WPB  4             // waves per block
#define GPB  16            // 16-lane row-groups per block
#define NBLOCKS 2048
#define NGROUPS (NBLOCKS * GPB)   // 32768
#define RA_ROWS (5 * NGROUPS)     // 163840 rows = 196.6 MB, L3-resident region

#define P2_BLOCKS  256
#define P2_THREADS 1024
#define P2_CPT     2       // ceil(400000/256/1024)
#define NCAND      (P2_BLOCKS * K)   // 2560
#define F_CPT      3       // ceil(2560/1024)

typedef float f32x4 __attribute__((ext_vector_type(4)));

__device__ __forceinline__ f32x4 ntload(const f32x4* p) {
    return __builtin_nontemporal_load(p);
}

__device__ __forceinline__ float d4(f32x4 a, f32x4 b) {
    return a[0]*b[0] + a[1]*b[1] + a[2]*b[2] + a[3]*b[3];
}

#define RED16(x) { x += __shfl_xor(x, 8, 64); x += __shfl_xor(x, 4, 64); \
                   x += __shfl_xor(x, 2, 64); x += __shfl_xor(x, 1, 64); }

// ---------------- Phase 1: cosine for ALL rows -> score[] ----------------
// 16 lanes per row, 4 consecutive rows per wave, strided groups.
// Region A (first RA rows, ~197MB): TEMPORAL loads -> lines allocate in L2/L3
//   and persist across graph replays (L3 = 256MB).
// Region B (rest, ~283MB): NON-TEMPORAL loads -> streamed, no cache thrash.
__global__ __launch_bounds__(256) void cos_all(
    const float* __restrict__ emb, const float* __restrict__ wvec,
    float* __restrict__ score, int V, int s, int RA)
{
    const int tid  = threadIdx.x;
    const int lane = tid & 63;
    const int wid  = tid >> 6;
    const int l16  = lane & 15;
    const int rg   = lane >> 4;
    const bool tl  = (l16 < NF4 - 64);     // 11 tail lanes

    const f32x4* w4p = (const f32x4*)wvec;
    f32x4 w0 = w4p[l16];
    f32x4 w1 = w4p[l16 + 16];
    f32x4 w2 = w4p[l16 + 32];
    f32x4 w3 = w4p[l16 + 48];
    f32x4 w4t = 0.f;
    if (tl) w4t = w4p[l16 + 64];

    float qsq = d4(w0,w0)+d4(w1,w1)+d4(w2,w2)+d4(w3,w3)+d4(w4t,w4t);
    RED16(qsq);
    const float qn = sqrtf(qsq);

    const int g0 = (blockIdx.x * WPB + wid) * 4 + rg;
    const size_t stepF4 = (size_t)s * NF4;

    const f32x4* p = (const f32x4*)emb + (size_t)g0 * NF4 + l16;

#define BODY(a0,a1,a2,a3,a4, ROW)                            \
    {   float da = d4(a0,w0) + d4(a1,w1);                    \
        float db = d4(a2,w2) + d4(a3,w3) + d4(a4,w4t);       \
        float sa = d4(a0,a0) + d4(a1,a1);                    \
        float sb = d4(a2,a2) + d4(a3,a3) + d4(a4,a4);        \
        float dot = da + db;                                 \
        float sq  = sa + sb;                                 \
        RED16(dot); RED16(sq);                               \
        float c = dot / (sqrtf(sq + 1e-9f) * qn);            \
        if (l16 == 0) score[ROW] = c; }

    int r = g0;
    // --- Region A: temporal loads (L3-persistent across replays) ---
    for (; r < RA; r += s, p += stepF4) {
        f32x4 a0 = p[0];
        f32x4 a1 = p[16];
        f32x4 a2 = p[32];
        f32x4 a3 = p[48];
        f32x4 a4 = 0.f;
        if (tl) a4 = p[64];
        BODY(a0,a1,a2,a3,a4, r)
    }
    // --- Region B: non-temporal loads (stream, don't evict region A) ---
    for (; r < V; r += s, p += stepF4) {
        f32x4 a0 = ntload(p);
        f32x4 a1 = ntload(p + 16);
        f32x4 a2 = ntload(p + 32);
        f32x4 a3 = ntload(p + 48);
        f32x4 a4 = 0.f;
        if (tl) a4 = ntload(p + 64);
        BODY(a0,a1,a2,a3,a4, r)
    }
#undef BODY
}

// ---------------- Phase 2a: exact per-block top-10 over score chunks ----------------
__global__ __launch_bounds__(P2_THREADS) void block_topk(
    const float* __restrict__ score, int V,
    float* __restrict__ cand_v, int* __restrict__ cand_i)
{
    __shared__ float rv[16];
    __shared__ int   rp[16];
    __shared__ int   s_bp;

    const int tid  = threadIdx.x;
    const int lane = tid & 63;
    const int wid  = tid >> 6;
    const int per  = (V + P2_BLOCKS - 1) / P2_BLOCKS;
    const int base = blockIdx.x * per;

    float v[P2_CPT];
    #pragma unroll
    for (int t = 0; t < P2_CPT; ++t) {
        int i = tid + t * P2_THREADS;
        v[t] = (i < per && base + i < V) ? score[base + i] : -3e38f;
    }

    for (int p = 0; p < K; ++p) {
        float bestv = -3e38f; int bestpos = 0x7fffffff;
        #pragma unroll
        for (int t = 0; t < P2_CPT; ++t) {
            if (v[t] > bestv) { bestv = v[t]; bestpos = tid + t * P2_THREADS; }
        }
        #pragma unroll
        for (int m = 32; m >= 1; m >>= 1) {
            float ov = __shfl_xor(bestv, m, 64);
            int   op = __shfl_xor(bestpos, m, 64);
            if (ov > bestv || (ov == bestv && op < bestpos)) { bestv = ov; bestpos = op; }
        }
        if (lane == 0) { rv[wid] = bestv; rp[wid] = bestpos; }
        __syncthreads();
        if (tid == 0) {
            float bv = rv[0]; int bp = rp[0];
            for (int i = 1; i < 16; ++i)
                if (rv[i] > bv || (rv[i] == bv && rp[i] < bp)) { bv = rv[i]; bp = rp[i]; }
            cand_v[blockIdx.x*K + p] = bv;
            cand_i[blockIdx.x*K + p] = base + bp;
            s_bp = bp;
        }
        __syncthreads();
        const int wbp = s_bp;
        #pragma unroll
        for (int t = 0; t < P2_CPT; ++t) {
            if (tid + t * P2_THREADS == wbp) v[t] = -3e38f;
        }
        __syncthreads();
    }
}

// ---------------- Phase 2b: final top-10 over 2560 candidates ----------------
__global__ __launch_bounds__(P2_THREADS) void final_topk(
    const float* __restrict__ cand_v, const int* __restrict__ cand_i,
    float* __restrict__ out)
{
    __shared__ float rv[16];
    __shared__ int   rp[16];
    __shared__ int   s_bp;

    const int tid  = threadIdx.x;
    const int lane = tid & 63;
    const int wid  = tid >> 6;

    float v[F_CPT];
    #pragma unroll
    for (int t = 0; t < F_CPT; ++t) {
        int i = tid + t * P2_THREADS;
        v[t] = (i < NCAND) ? cand_v[i] : -3e38f;
    }

    for (int p = 0; p < K; ++p) {
        float bestv = -3e38f; int bestpos = 0x7fffffff;
        #pragma unroll
        for (int t = 0; t < F_CPT; ++t) {
            if (v[t] > bestv) { bestv = v[t]; bestpos = tid + t * P2_THREADS; }
        }
        #pragma unroll
        for (int m = 32; m >= 1; m >>= 1) {
            float ov = __shfl_xor(bestv, m, 64);
            int   op = __shfl_xor(bestpos, m, 64);
            if (ov > bestv || (ov == bestv && op < bestpos)) { bestv = ov; bestpos = op; }
        }
        if (lane == 0) { rv[wid] = bestv; rp[wid] = bestpos; }
        __syncthreads();
        if (tid == 0) {
            float bv = rv[0]; int bp = rp[0];
            for (int i = 1; i < 16; ++i)
                if (rv[i] > bv || (rv[i] == bv && rp[i] < bp)) { bv = rv[i]; bp = rp[i]; }
            out[p]     = bv;
            out[K + p] = (float)cand_i[bp];     // exact < 2^24
            s_bp = bp;
        }
        __syncthreads();
        const int wbp = s_bp;
        #pragma unroll
        for (int t = 0; t < F_CPT; ++t) {
            if (tid + t * P2_THREADS == wbp) v[t] = -3e38f;
        }
        __syncthreads();
    }
}

extern "C" void kernel_launch(void* const* d_in, const int* in_sizes, int n_in,
                              void* d_out, int out_size, void* d_ws, size_t ws_size,
                              hipStream_t stream) {
    const float* emb  = (const float*)d_in[0];
    const float* wvec = (const float*)d_in[1];
    const int V = in_sizes[0] / D;

    int RA = RA_ROWS;
    if (RA > V) RA = V;

    float* score  = (float*)d_ws;
    float* cand_v = score + V;
    int*   cand_i = (int*)(cand_v + NCAND);

    cos_all<<<NBLOCKS, 256, 0, stream>>>(emb, wvec, score, V, NGROUPS, RA);
    block_topk<<<P2_BLOCKS, P2_THREADS, 0, stream>>>(score, V, cand_v, cand_i);
    final_topk<<<1, P2_THREADS, 0, stream>>>(cand_v, cand_i, (float*)d_out);
}